// Round 10
// baseline (478.266 us; speedup 1.0000x reference)
//
#include <hip/hip_runtime.h>
#include <hip/hip_bf16.h>
#include <stdint.h>
#include <stddef.h>

#define Bd  4
#define Sd  1024
#define Hd  1024
#define NHd 16
#define DKd 64
#define SCALEF 0.125f
#define NEGV  -9.0e15f
#define L2E   1.4426950408889634f

typedef __attribute__((ext_vector_type(8))) short bfrag;   // 8 bf16 = 4 VGPRs (MFMA A/B)
typedef __attribute__((ext_vector_type(4))) float facc;    // 4 fp32 (MFMA C/D)
typedef __attribute__((ext_vector_type(4))) float f32x4;   // clang-native float4

typedef __attribute__((address_space(1))) const unsigned int ga_u32;
typedef __attribute__((address_space(3))) unsigned int ls_u32;

__device__ __forceinline__ void gload_lds16(const void* g, void* l) {
  // async global->LDS: global addr per-lane, LDS dest = wave-uniform base + lane*16
  __builtin_amdgcn_global_load_lds((ga_u32*)g, (ls_u32*)l, 16, 0, 0);
}

__device__ __forceinline__ unsigned short f2bf(float f) {
  unsigned int u = __float_as_uint(f);
  u += 0x7fffu + ((u >> 16) & 1u);   // RNE
  return (unsigned short)(u >> 16);
}

// ---------------- fused cast fp32 -> bf16, all 5 arrays, one launch ----------------
__global__ void castk_all(const float* __restrict__ s0, const float* __restrict__ s1,
                          const float* __restrict__ s2, const float* __restrict__ s3,
                          const float* __restrict__ s4,
                          unsigned short* __restrict__ d0, unsigned short* __restrict__ d1,
                          unsigned short* __restrict__ d2, unsigned short* __restrict__ d3,
                          unsigned short* __restrict__ d4) {
  const int id = blockIdx.x;
  const float* s; unsigned short* d; int i;
  if (id < 4096) { s = s0; d = d0; i = id * 256 + threadIdx.x; }
  else {
    const int w = (id - 4096) >> 10;
    s = (w == 0) ? s1 : (w == 1) ? s2 : (w == 2) ? s3 : s4;
    d = (w == 0) ? d1 : (w == 1) ? d2 : (w == 2) ? d3 : d4;
    i = ((id - 4096) & 1023) * 256 + threadIdx.x;
  }
  float4 v = ((const float4*)s)[i];
  ushort4 ov;
  ov.x = f2bf(v.x); ov.y = f2bf(v.y); ov.z = f2bf(v.z); ov.w = f2bf(v.w);
  ((ushort4*)d)[i] = ov;
}

// ---------------- fused QKV projection GEMM (2-phase double-buffered staging) ----------------
__global__ __launch_bounds__(256, 3)
void gemm_qkv(const unsigned short* __restrict__ A,
              const unsigned short* __restrict__ W0, const unsigned short* __restrict__ W1,
              const unsigned short* __restrict__ W2,
              const float* __restrict__ b0, const float* __restrict__ b1, const float* __restrict__ b2,
              unsigned short* __restrict__ o0, unsigned short* __restrict__ o1, unsigned short* __restrict__ o2) {
  __shared__ __align__(16) unsigned short smem[128 * 136];
  const int z = blockIdx.z;
  const unsigned short* Bm = (z == 0) ? W0 : (z == 1) ? W1 : W2;
  const float* bias = (z == 0) ? b0 : (z == 1) ? b1 : b2;
  unsigned short* out = (z == 0) ? o0 : (z == 1) ? o1 : o2;

  const int m0 = blockIdx.x * 128, n0 = blockIdx.y * 128;
  const int tid = threadIdx.x;
  const int wave = tid >> 6, lane = tid & 63;
  const int quad = lane >> 4, l16 = lane & 15;
  const int wm = wave >> 1, wn = wave & 1;

  facc acc[4][4] = {};

  const int j0 = wave * 128 + lane;
  const int j1 = j0 + 64;
  const int row0 = j0 >> 2, ko0 = (j0 & 3) << 3;
  const int row1 = j1 >> 2, ko1 = (j1 & 3) << 3;
  const size_t aoff0 = (size_t)(m0 + row0) * 1024 + ko0;
  const size_t aoff1 = (size_t)(m0 + row1) * 1024 + ko1;
  const size_t boff0 = (size_t)(n0 + row0) * 1024 + ko0;
  const size_t boff1 = (size_t)(n0 + row1) * 1024 + ko1;

  const int stA = (wave * 2 + 0) * 512;
  const int stA1i = (wave * 2 + 1) * 512;

  gload_lds16(A + aoff0, smem + stA);
  gload_lds16(A + aoff1, smem + stA1i);
  gload_lds16(Bm + boff0, smem + 8192 + stA);
  gload_lds16(Bm + boff1, smem + 8192 + stA1i);
  __syncthreads();

  for (int k0 = 0; k0 < 1024; k0 += 32) {
    const int cur = (k0 >> 5) & 1;
    const int nxt = cur ^ 1;
    if (k0 < 992) {
      unsigned short* dA = smem + nxt * 4096;
      unsigned short* dB = smem + 8192 + nxt * 4096;
      gload_lds16(A + aoff0 + k0 + 32, dA + stA);
      gload_lds16(A + aoff1 + k0 + 32, dA + stA1i);
      gload_lds16(Bm + boff0 + k0 + 32, dB + stA);
      gload_lds16(Bm + boff1 + k0 + 32, dB + stA1i);
    }
    const unsigned short* sA = smem + cur * 4096;
    const unsigned short* sB = smem + 8192 + cur * 4096;
    bfrag af[4], bf[4];
#pragma unroll
    for (int i = 0; i < 4; ++i) af[i] = *(const bfrag*)(sA + (wm * 64 + i * 16 + l16) * 32 + quad * 8);
#pragma unroll
    for (int j = 0; j < 4; ++j) bf[j] = *(const bfrag*)(sB + (wn * 64 + j * 16 + l16) * 32 + quad * 8);
#pragma unroll
    for (int i = 0; i < 4; ++i)
#pragma unroll
      for (int j = 0; j < 4; ++j)
        acc[i][j] = __builtin_amdgcn_mfma_f32_16x16x32_bf16(af[i], bf[j], acc[i][j], 0, 0, 0);
    __syncthreads();
  }

  if (z < 2) {
#pragma unroll
    for (int i = 0; i < 4; ++i)
#pragma unroll
      for (int j = 0; j < 4; ++j) {
        const int col = n0 + wn * 64 + j * 16 + l16;
        const float bv = bias[col];
        const int h = col >> 6, d = col & 63;
#pragma unroll
        for (int r = 0; r < 4; ++r) {
          const int m = m0 + wm * 64 + i * 16 + quad * 4 + r;
          const int b = m >> 10, s = m & 1023;
          out[(((size_t)(b * NHd + h) * Sd) + s) * DKd + d] = f2bf(acc[i][j][r] + bv);
        }
      }
  } else {
    unsigned short* sT = smem;  // 128 x 136 (padded), reuses dbuf area (post-barrier)
#pragma unroll
    for (int i = 0; i < 4; ++i)
#pragma unroll
      for (int j = 0; j < 4; ++j) {
        const int col = n0 + wn * 64 + j * 16 + l16;
        const float bv = bias[col];
        const int nrow = wn * 64 + j * 16 + l16;
        const int mbase = wm * 64 + i * 16 + quad * 4;
        ushort4 pk;
        pk.x = f2bf(acc[i][j][0] + bv);
        pk.y = f2bf(acc[i][j][1] + bv);
        pk.z = f2bf(acc[i][j][2] + bv);
        pk.w = f2bf(acc[i][j][3] + bv);
        *(ushort4*)(sT + nrow * 136 + mbase) = pk;
      }
    __syncthreads();
    const int bI = m0 >> 10, s0i = m0 & 1023;
#pragma unroll
    for (int it = 0; it < 8; ++it) {
      const int c = tid + it * 256;
      const int row = c >> 4, mc = (c & 15) * 8;
      bfrag vv = *(const bfrag*)(sT + row * 136 + mc);
      const int col = n0 + row, hh = col >> 6, dd = col & 63;
      *(bfrag*)(out + (((size_t)(bI * NHd + hh) * DKd) + dd) * Sd + s0i + mc) = vv;
    }
  }
}

// ---------------- output projection GEMM: 64x128 tile, BK=64, swizzled LDS, 2-phase ----------------
__global__ __launch_bounds__(256, 3)
void gemm_out(const unsigned short* __restrict__ A, const unsigned short* __restrict__ Bm,
              const float* __restrict__ bias, float* __restrict__ out) {
  __shared__ __align__(16) unsigned short smem[24576];
  const int m0 = blockIdx.x * 64, n0 = blockIdx.y * 128;
  const int tid = threadIdx.x;
  const int wave = tid >> 6, lane = tid & 63;
  const int quad = lane >> 4, l16 = lane & 15;

  facc acc[8] = {};

  const int cA0 = (wave * 2 + 0) * 64 + lane;
  const int cA1 = (wave * 2 + 1) * 64 + lane;
  const int rA0 = cA0 >> 3, kA0 = ((cA0 & 7) ^ (rA0 & 7)) * 8;
  const int rA1 = cA1 >> 3, kA1 = ((cA1 & 7) ^ (rA1 & 7)) * 8;
  const size_t aoff0 = (size_t)(m0 + rA0) * 1024 + kA0;
  const size_t aoff1 = (size_t)(m0 + rA1) * 1024 + kA1;
  size_t boff[4];
#pragma unroll
  for (int i = 0; i < 4; ++i) {
    const int c = (wave * 4 + i) * 64 + lane;
    const int r = c >> 3, kk = ((c & 7) ^ (r & 7)) * 8;
    boff[i] = (size_t)(n0 + r) * 1024 + kk;
  }

  const int stA0 = (wave * 2 + 0) * 512;
  const int stA1i = (wave * 2 + 1) * 512;

  gload_lds16(A + aoff0, smem + stA0);
  gload_lds16(A + aoff1, smem + stA1i);
#pragma unroll
  for (int i = 0; i < 4; ++i)
    gload_lds16(Bm + boff[i], smem + 8192 + (wave * 4 + i) * 512);
  __syncthreads();

  for (int k0 = 0; k0 < 1024; k0 += 64) {
    const int cur = (k0 >> 6) & 1;
    const int nxt = cur ^ 1;
    if (k0 < 960) {
      unsigned short* dA = smem + nxt * 4096;
      unsigned short* dB = smem + 8192 + nxt * 8192;
      gload_lds16(A + aoff0 + k0 + 64, dA + stA0);
      gload_lds16(A + aoff1 + k0 + 64, dA + stA1i);
#pragma unroll
      for (int i = 0; i < 4; ++i)
        gload_lds16(Bm + boff[i] + k0 + 64, dB + (wave * 4 + i) * 512);
    }
    const unsigned short* sA = smem + cur * 4096;
    const unsigned short* sB = smem + 8192 + cur * 8192;
#pragma unroll
    for (int c2 = 0; c2 < 2; ++c2) {
      const int ko = ((c2 * 4 + quad) ^ (l16 & 7)) * 8;   // unswizzle
      bfrag af = *(const bfrag*)(sA + (wave * 16 + l16) * 64 + ko);
#pragma unroll
      for (int j = 0; j < 8; ++j) {
        bfrag bf = *(const bfrag*)(sB + (j * 16 + l16) * 64 + ko);
        acc[j] = __builtin_amdgcn_mfma_f32_16x16x32_bf16(af, bf, acc[j], 0, 0, 0);
      }
    }
    __syncthreads();
  }

#pragma unroll
  for (int j = 0; j < 8; ++j) {
    const int col = n0 + j * 16 + l16;
    const float bv = bias[col];
#pragma unroll
    for (int r = 0; r < 4; ++r) {
      const int m = m0 + wave * 16 + quad * 4 + r;
      out[(size_t)m * 1024 + col] = acc[j][r] + bv;
    }
  }
}

// ---------------- fused flash attention: K/V/BIAS all via DMA-to-LDS ----------------
// grid: 512 blocks x 512 thr (8 waves), 2 blocks/CU (LDS 58 KB). Block = 128
// q-rows x full KV in 32 tiles of kv=32. ALL streams (K, V, bias f32) staged
// by global_load_lds into double-buffered XOR-swizzled LDS, issued one tile
// ahead and drained by the per-tile barrier. Rationale: the bias-in-VGPR path
// (NT loads + asm pin) could be sunk-to-use by the allocator, re-exposing
// ~900cy HBM latency per tile (attn stuck ~2x its 41us bias-read floor). DMA
// issue sites can't be sunk; the barrier guarantees residency. Swizzles
// (involution on both DMA source and read side): K/bias slot^=row&7 (2-way
// max), V slot^=(row^(row>>2))&3 (2-way max).
__global__ __attribute__((amdgpu_flat_work_group_size(512, 512)))
void attn_kernel(const unsigned short* __restrict__ q,   // [B,NH,S,DK]
                 const unsigned short* __restrict__ k,   // [B,NH,S,DK]
                 const unsigned short* __restrict__ vt,  // [B,NH,DK,S]
                 const float* __restrict__ bias,         // [B,NH,S,S]
                 unsigned short* __restrict__ o)         // [B,S,HID] bf16
{
  __shared__ __align__(16) unsigned short sK[2][2048];   // 2 x 4 KB: [32 krows][64] swz
  __shared__ __align__(16) unsigned short sV[2][2048];   // 2 x 4 KB: [64 drows][32] swz
  __shared__ __align__(16) float sB[2][4096];            // 2 x 16 KB: [128 qrows][32] swz
  __shared__ __align__(16) unsigned int sP[8][16][20];   // 10.2 KB packed-P (stride 80B)

  const int p = blockIdx.x;
  const int xcd = p & 7;
  const int g = p >> 3;                   // 0..63
  const int bh = ((g >> 3) << 3) | xcd;   // 8 bh per XCD (bijective)
  const int qblk = g & 7;
  const int tid = threadIdx.x;
  const int wave = tid >> 6, lane = tid & 63;
  const int quad = lane >> 4, l16 = lane & 15;
  const int b = bh >> 4, h = bh & 15;

  const unsigned short* qh = q + (size_t)bh * Sd * DKd;
  const unsigned short* kh = k + (size_t)bh * Sd * DKd;
  const unsigned short* vh = vt + (size_t)bh * DKd * Sd;
  const float* bias_h = bias + (size_t)bh * Sd * Sd;
  const int q0 = qblk * 128;
  const int rq = q0 + wave * 16;
  unsigned int (*sPw)[20] = sP[wave];

  // ---- DMA geometry ----
  // K: threads 0..255 cover 32 rows x 8 slots; V: threads 256..511 cover 64 rows x 4 slots.
  const int cKV = tid & 255;
  const int isV = tid >> 8;
  const int krow = cKV >> 3, kslot = (cKV & 7) ^ (krow & 7);
  const int vrow = cKV >> 2, vslot = (cKV & 3) ^ ((vrow ^ (vrow >> 2)) & 3);
  const unsigned short* srcKV = isV ? (vh + (size_t)vrow * Sd + vslot * 8)
                                    : (kh + (size_t)krow * DKd + kslot * 8);
  const int kvTileStep = isV ? 32 : 32 * DKd;    // elements per tile advance
  const int dKVoff = (wave & 3) * 512;           // wave-uniform LDS base (ushorts)
  // bias: 2 rounds x 512 threads cover 128 rows x 8 slots (16B = 4 floats each)
  const int bc0 = tid, bc1 = tid + 512;
  const int brow0 = bc0 >> 3, bslot0 = (bc0 & 7) ^ (brow0 & 7);
  const int brow1 = bc1 >> 3, bslot1 = (bc1 & 7) ^ (brow1 & 7);
  const float* srcB0 = bias_h + (size_t)(q0 + brow0) * Sd + bslot0 * 4;
  const float* srcB1 = bias_h + (size_t)(q0 + brow1) * Sd + bslot1 * 4;
  const int dB0 = wave * 256;                    // float idx, wave-uniform (round 0)
  const int dB1 = 2048 + wave * 256;             // round 1

  bfrag qf[2];
#pragma unroll
  for (int c = 0; c < 2; ++c)
    qf[c] = *(const bfrag*)(qh + (size_t)(rq + l16) * DKd + c * 32 + quad * 8);

  facc oacc[4] = {};
  float lsum = 0.f;
  const float SL2 = SCALEF * L2E;

  // ---- prologue: stage tile 0 into buffer 0 ----
  gload_lds16(srcKV, (isV ? sV[0] : sK[0]) + dKVoff);
  gload_lds16(srcB0, sB[0] + dB0);
  gload_lds16(srcB1, sB[0] + dB1);
  __syncthreads();

  for (int t = 0; t < 32; ++t) {
    const int bb = t & 1;
    // ---- issue DMA for tile t+1 into the other buffers (drained at barrier) ----
    if (t < 31) {
      const int adv = (t + 1) * kvTileStep;
      gload_lds16(srcKV + adv, (isV ? sV[bb ^ 1] : sK[bb ^ 1]) + dKVoff);
      gload_lds16(srcB0 + (t + 1) * 32, sB[bb ^ 1] + dB0);
      gload_lds16(srcB1 + (t + 1) * 32, sB[bb ^ 1] + dB1);
    }
    // ---- S^T = K Q^T from LDS: sacc[j][r] = S[t*32 + j*16+quad*4+r][rq+l16] ----
    facc sacc[2] = {};
#pragma unroll
    for (int cc = 0; cc < 2; ++cc)
#pragma unroll
      for (int j = 0; j < 2; ++j) {
        const int row = j * 16 + l16;
        const int slot = ((cc * 4 + quad) ^ (row & 7));
        bfrag kf = *(const bfrag*)(sK[bb] + row * 64 + slot * 8);
        sacc[j] = __builtin_amdgcn_mfma_f32_16x16x32_bf16(kf, qf[cc], sacc[j], 0, 0, 0);
      }
    // ---- exp/mask: bias from LDS (f32x4, swizzled) ----
    unsigned int pk[2][2];
#pragma unroll
    for (int j = 0; j < 2; ++j) {
      const int brow = wave * 16 + l16;
      const int bslot = (j * 4 + quad) ^ (brow & 7);
      const f32x4 bv = *(const f32x4*)(sB[bb] + brow * 32 + bslot * 4);
      float e0 = __builtin_amdgcn_exp2f(fmaf(sacc[j][0], SL2, bv.x * L2E));
      float e1 = __builtin_amdgcn_exp2f(fmaf(sacc[j][1], SL2, bv.y * L2E));
      float e2 = __builtin_amdgcn_exp2f(fmaf(sacc[j][2], SL2, bv.z * L2E));
      float e3 = __builtin_amdgcn_exp2f(fmaf(sacc[j][3], SL2, bv.w * L2E));
      e0 = (sacc[j][0] == 0.f) ? 0.f : e0;
      e1 = (sacc[j][1] == 0.f) ? 0.f : e1;
      e2 = (sacc[j][2] == 0.f) ? 0.f : e2;
      e3 = (sacc[j][3] == 0.f) ? 0.f : e3;
      lsum += (e0 + e1) + (e2 + e3);
      pk[j][0] = (unsigned int)f2bf(e0) | ((unsigned int)f2bf(e1) << 16);
      pk[j][1] = (unsigned int)f2bf(e2) | ((unsigned int)f2bf(e3) << 16);
    }
    // ---- reshape P^T via wave-private LDS ----
#pragma unroll
    for (int j = 0; j < 2; ++j) {
      uint2 w; w.x = pk[j][0]; w.y = pk[j][1];
      *(uint2*)&sPw[l16][j * 8 + quad * 2] = w;
    }
    // ---- O^T += V^T P^T from LDS ----
    {
      bfrag pf = *(const bfrag*)&sPw[l16][quad * 4];
#pragma unroll
      for (int n = 0; n < 4; ++n) {
        const int row = n * 16 + l16;
        const int slot = quad ^ ((row ^ (row >> 2)) & 3);
        bfrag vf = *(const bfrag*)(sV[bb] + row * 32 + slot * 8);
        oacc[n] = __builtin_amdgcn_mfma_f32_16x16x32_bf16(vf, pf, oacc[n], 0, 0, 0);
      }
    }
    // ---- barrier: all reads of buf bb done; DMA into bb^1 drained ----
    __syncthreads();
  }

  // ---- row-sum: lane owns q-row l16; partials across quads ----
  lsum += __shfl_xor(lsum, 16, 64);
  lsum += __shfl_xor(lsum, 32, 64);
  const float rinv = 1.0f / lsum;

  const size_t rowo = (size_t)(b * Sd + rq + l16) * Hd + h * 64 + quad * 4;
#pragma unroll
  for (int n = 0; n < 4; ++n) {
    ushort4 st;
    st.x = f2bf(oacc[n][0] * rinv);
    st.y = f2bf(oacc[n][1] * rinv);
    st.z = f2bf(oacc[n][2] * rinv);
    st.w = f2bf(oacc[n][3] * rinv);
    *(ushort4*)(o + rowo + n * 16) = st;
  }
}

extern "C" void kernel_launch(void* const* d_in, const int* in_sizes, int n_in,
                              void* d_out, int out_size, void* d_ws, size_t ws_size,
                              hipStream_t stream) {
  const float* batch = (const float*)d_in[0];
  const float* attn_bias = (const float*)d_in[1];
  const float* Wq = (const float*)d_in[2];
  const float* bq = (const float*)d_in[3];
  const float* Wk = (const float*)d_in[4];
  const float* bk = (const float*)d_in[5];
  const float* Wv = (const float*)d_in[6];
  const float* bv = (const float*)d_in[7];
  const float* Wo = (const float*)d_in[8];
  const float* bo = (const float*)d_in[9];
  float* out = (float*)d_out;

  unsigned short* ws = (unsigned short*)d_ws;
  unsigned short* Ab  = ws;                 // 4096x1024
  unsigned short* Wqb = Ab  + 4194304;      // 1024x1024 each
  unsigned short* Wkb = Wqb + 1048576;
  unsigned short* Wvb = Wkb + 1048576;
  unsigned short* Wob = Wvb + 1048576;
  unsigned short* qb  = Wob + 1048576;      // [B,NH,S,DK]
  unsigned short* kb  = qb  + 4194304;
  unsigned short* vtb = kb  + 4194304;      // [B,NH,DK,S]
  unsigned short* ob  = vtb + 4194304;      // [B,S,HID]

  castk_all<<<8192, 256, 0, stream>>>(batch, Wq, Wk, Wv, Wo, Ab, Wqb, Wkb, Wvb, Wob);
  gemm_qkv<<<dim3(32, 8, 3), 256, 0, stream>>>(Ab, Wqb, Wkb, Wvb, bq, bk, bv, qb, kb, vtb);
  attn_kernel<<<dim3(512), 512, 0, stream>>>(qb, kb, vtb, attn_bias, ob);
  gemm_out<<<dim3(64, 8), 256, 0, stream>>>(ob, Wob, bo, out);
}

// Round 11
// 468.951 us; speedup vs baseline: 1.0199x; 1.0199x over previous
//
#include <hip/hip_runtime.h>
#include <hip/hip_bf16.h>
#include <stdint.h>
#include <stddef.h>

#define Bd  4
#define Sd  1024
#define Hd  1024
#define NHd 16
#define DKd 64
#define SCALEF 0.125f
#define NEGV  -9.0e15f
#define L2E   1.4426950408889634f

typedef __attribute__((ext_vector_type(8))) short bfrag;   // 8 bf16 = 4 VGPRs (MFMA A/B)
typedef __attribute__((ext_vector_type(4))) float facc;    // 4 fp32 (MFMA C/D)
typedef __attribute__((ext_vector_type(4))) float f32x4;   // clang-native float4

typedef __attribute__((address_space(1))) const unsigned int ga_u32;
typedef __attribute__((address_space(3))) unsigned int ls_u32;

__device__ __forceinline__ void gload_lds16(const void* g, void* l) {
  // async global->LDS: global addr per-lane, LDS dest = wave-uniform base + lane*16
  __builtin_amdgcn_global_load_lds((ga_u32*)g, (ls_u32*)l, 16, 0, 0);
}

// bias load pinned at issue site (asm volatile cannot be sunk by the
// scheduler); residency is guaranteed by the next __syncthreads(), whose
// s_waitcnt vmcnt(0) (emitted for the K/V global_load_lds DMAs) drains
// this load too.
__device__ __forceinline__ void bias_load4(f32x4& dst, const float* p) {
  asm volatile("global_load_dwordx4 %0, %1, off" : "=v"(dst) : "v"(p));
}

__device__ __forceinline__ unsigned short f2bf(float f) {
  unsigned int u = __float_as_uint(f);
  u += 0x7fffu + ((u >> 16) & 1u);   // RNE
  return (unsigned short)(u >> 16);
}

// ---------------- fused cast fp32 -> bf16, all 5 arrays, one launch ----------------
__global__ void castk_all(const float* __restrict__ s0, const float* __restrict__ s1,
                          const float* __restrict__ s2, const float* __restrict__ s3,
                          const float* __restrict__ s4,
                          unsigned short* __restrict__ d0, unsigned short* __restrict__ d1,
                          unsigned short* __restrict__ d2, unsigned short* __restrict__ d3,
                          unsigned short* __restrict__ d4) {
  const int id = blockIdx.x;
  const float* s; unsigned short* d; int i;
  if (id < 4096) { s = s0; d = d0; i = id * 256 + threadIdx.x; }
  else {
    const int w = (id - 4096) >> 10;
    s = (w == 0) ? s1 : (w == 1) ? s2 : (w == 2) ? s3 : s4;
    d = (w == 0) ? d1 : (w == 1) ? d2 : (w == 2) ? d3 : d4;
    i = ((id - 4096) & 1023) * 256 + threadIdx.x;
  }
  float4 v = ((const float4*)s)[i];
  ushort4 ov;
  ov.x = f2bf(v.x); ov.y = f2bf(v.y); ov.z = f2bf(v.z); ov.w = f2bf(v.w);
  ((ushort4*)d)[i] = ov;
}

// ---------------- fused QKV projection GEMM (2-phase double-buffered staging) ----------------
__global__ __launch_bounds__(256, 3)
void gemm_qkv(const unsigned short* __restrict__ A,
              const unsigned short* __restrict__ W0, const unsigned short* __restrict__ W1,
              const unsigned short* __restrict__ W2,
              const float* __restrict__ b0, const float* __restrict__ b1, const float* __restrict__ b2,
              unsigned short* __restrict__ o0, unsigned short* __restrict__ o1, unsigned short* __restrict__ o2) {
  __shared__ __align__(16) unsigned short smem[128 * 136];
  const int z = blockIdx.z;
  const unsigned short* Bm = (z == 0) ? W0 : (z == 1) ? W1 : W2;
  const float* bias = (z == 0) ? b0 : (z == 1) ? b1 : b2;
  unsigned short* out = (z == 0) ? o0 : (z == 1) ? o1 : o2;

  const int m0 = blockIdx.x * 128, n0 = blockIdx.y * 128;
  const int tid = threadIdx.x;
  const int wave = tid >> 6, lane = tid & 63;
  const int quad = lane >> 4, l16 = lane & 15;
  const int wm = wave >> 1, wn = wave & 1;

  facc acc[4][4] = {};

  const int j0 = wave * 128 + lane;
  const int j1 = j0 + 64;
  const int row0 = j0 >> 2, ko0 = (j0 & 3) << 3;
  const int row1 = j1 >> 2, ko1 = (j1 & 3) << 3;
  const size_t aoff0 = (size_t)(m0 + row0) * 1024 + ko0;
  const size_t aoff1 = (size_t)(m0 + row1) * 1024 + ko1;
  const size_t boff0 = (size_t)(n0 + row0) * 1024 + ko0;
  const size_t boff1 = (size_t)(n0 + row1) * 1024 + ko1;

  const int stA = (wave * 2 + 0) * 512;
  const int stA1i = (wave * 2 + 1) * 512;

  gload_lds16(A + aoff0, smem + stA);
  gload_lds16(A + aoff1, smem + stA1i);
  gload_lds16(Bm + boff0, smem + 8192 + stA);
  gload_lds16(Bm + boff1, smem + 8192 + stA1i);
  __syncthreads();

  for (int k0 = 0; k0 < 1024; k0 += 32) {
    const int cur = (k0 >> 5) & 1;
    const int nxt = cur ^ 1;
    if (k0 < 992) {
      unsigned short* dA = smem + nxt * 4096;
      unsigned short* dB = smem + 8192 + nxt * 4096;
      gload_lds16(A + aoff0 + k0 + 32, dA + stA);
      gload_lds16(A + aoff1 + k0 + 32, dA + stA1i);
      gload_lds16(Bm + boff0 + k0 + 32, dB + stA);
      gload_lds16(Bm + boff1 + k0 + 32, dB + stA1i);
    }
    const unsigned short* sA = smem + cur * 4096;
    const unsigned short* sB = smem + 8192 + cur * 4096;
    bfrag af[4], bf[4];
#pragma unroll
    for (int i = 0; i < 4; ++i) af[i] = *(const bfrag*)(sA + (wm * 64 + i * 16 + l16) * 32 + quad * 8);
#pragma unroll
    for (int j = 0; j < 4; ++j) bf[j] = *(const bfrag*)(sB + (wn * 64 + j * 16 + l16) * 32 + quad * 8);
#pragma unroll
    for (int i = 0; i < 4; ++i)
#pragma unroll
      for (int j = 0; j < 4; ++j)
        acc[i][j] = __builtin_amdgcn_mfma_f32_16x16x32_bf16(af[i], bf[j], acc[i][j], 0, 0, 0);
    __syncthreads();
  }

  if (z < 2) {
#pragma unroll
    for (int i = 0; i < 4; ++i)
#pragma unroll
      for (int j = 0; j < 4; ++j) {
        const int col = n0 + wn * 64 + j * 16 + l16;
        const float bv = bias[col];
        const int h = col >> 6, d = col & 63;
#pragma unroll
        for (int r = 0; r < 4; ++r) {
          const int m = m0 + wm * 64 + i * 16 + quad * 4 + r;
          const int b = m >> 10, s = m & 1023;
          out[(((size_t)(b * NHd + h) * Sd) + s) * DKd + d] = f2bf(acc[i][j][r] + bv);
        }
      }
  } else {
    unsigned short* sT = smem;  // 128 x 136 (padded), reuses dbuf area (post-barrier)
#pragma unroll
    for (int i = 0; i < 4; ++i)
#pragma unroll
      for (int j = 0; j < 4; ++j) {
        const int col = n0 + wn * 64 + j * 16 + l16;
        const float bv = bias[col];
        const int nrow = wn * 64 + j * 16 + l16;
        const int mbase = wm * 64 + i * 16 + quad * 4;
        ushort4 pk;
        pk.x = f2bf(acc[i][j][0] + bv);
        pk.y = f2bf(acc[i][j][1] + bv);
        pk.z = f2bf(acc[i][j][2] + bv);
        pk.w = f2bf(acc[i][j][3] + bv);
        *(ushort4*)(sT + nrow * 136 + mbase) = pk;
      }
    __syncthreads();
    const int bI = m0 >> 10, s0i = m0 & 1023;
#pragma unroll
    for (int it = 0; it < 8; ++it) {
      const int c = tid + it * 256;
      const int row = c >> 4, mc = (c & 15) * 8;
      bfrag vv = *(const bfrag*)(sT + row * 136 + mc);
      const int col = n0 + row, hh = col >> 6, dd = col & 63;
      *(bfrag*)(out + (((size_t)(bI * NHd + hh) * DKd) + dd) * Sd + s0i + mc) = vv;
    }
  }
}

// ---------------- output projection GEMM: 64x128 tile, BK=64, swizzled LDS, 2-phase ----------------
__global__ __launch_bounds__(256, 3)
void gemm_out(const unsigned short* __restrict__ A, const unsigned short* __restrict__ Bm,
              const float* __restrict__ bias, float* __restrict__ out) {
  __shared__ __align__(16) unsigned short smem[24576];
  const int m0 = blockIdx.x * 64, n0 = blockIdx.y * 128;
  const int tid = threadIdx.x;
  const int wave = tid >> 6, lane = tid & 63;
  const int quad = lane >> 4, l16 = lane & 15;

  facc acc[8] = {};

  const int cA0 = (wave * 2 + 0) * 64 + lane;
  const int cA1 = (wave * 2 + 1) * 64 + lane;
  const int rA0 = cA0 >> 3, kA0 = ((cA0 & 7) ^ (rA0 & 7)) * 8;
  const int rA1 = cA1 >> 3, kA1 = ((cA1 & 7) ^ (rA1 & 7)) * 8;
  const size_t aoff0 = (size_t)(m0 + rA0) * 1024 + kA0;
  const size_t aoff1 = (size_t)(m0 + rA1) * 1024 + kA1;
  size_t boff[4];
#pragma unroll
  for (int i = 0; i < 4; ++i) {
    const int c = (wave * 4 + i) * 64 + lane;
    const int r = c >> 3, kk = ((c & 7) ^ (r & 7)) * 8;
    boff[i] = (size_t)(n0 + r) * 1024 + kk;
  }

  const int stA0 = (wave * 2 + 0) * 512;
  const int stA1i = (wave * 2 + 1) * 512;

  gload_lds16(A + aoff0, smem + stA0);
  gload_lds16(A + aoff1, smem + stA1i);
#pragma unroll
  for (int i = 0; i < 4; ++i)
    gload_lds16(Bm + boff[i], smem + 8192 + (wave * 4 + i) * 512);
  __syncthreads();

  for (int k0 = 0; k0 < 1024; k0 += 64) {
    const int cur = (k0 >> 6) & 1;
    const int nxt = cur ^ 1;
    if (k0 < 960) {
      unsigned short* dA = smem + nxt * 4096;
      unsigned short* dB = smem + 8192 + nxt * 8192;
      gload_lds16(A + aoff0 + k0 + 64, dA + stA0);
      gload_lds16(A + aoff1 + k0 + 64, dA + stA1i);
#pragma unroll
      for (int i = 0; i < 4; ++i)
        gload_lds16(Bm + boff[i] + k0 + 64, dB + (wave * 4 + i) * 512);
    }
    const unsigned short* sA = smem + cur * 4096;
    const unsigned short* sB = smem + 8192 + cur * 8192;
#pragma unroll
    for (int c2 = 0; c2 < 2; ++c2) {
      const int ko = ((c2 * 4 + quad) ^ (l16 & 7)) * 8;   // unswizzle
      bfrag af = *(const bfrag*)(sA + (wave * 16 + l16) * 64 + ko);
#pragma unroll
      for (int j = 0; j < 8; ++j) {
        bfrag bf = *(const bfrag*)(sB + (j * 16 + l16) * 64 + ko);
        acc[j] = __builtin_amdgcn_mfma_f32_16x16x32_bf16(af, bf, acc[j], 0, 0, 0);
      }
    }
    __syncthreads();
  }

#pragma unroll
  for (int j = 0; j < 8; ++j) {
    const int col = n0 + j * 16 + l16;
    const float bv = bias[col];
#pragma unroll
    for (int r = 0; r < 4; ++r) {
      const int m = m0 + wave * 16 + quad * 4 + r;
      out[(size_t)m * 1024 + col] = acc[j][r] + bv;
    }
  }
}

// ---------------- fused flash attention: LDS-staged K/V shared by 8 waves ----------------
// r9 structure (kv=64, 16 tiles, 50 KB LDS -> 3 blocks/CU, 24 waves/CU)
// with ONE change: bias prefetch issued via asm-volatile global_load_dwordx4
// (pinned at issue site, cannot be sunk to use); the per-tile barrier's
// vmcnt(0) drain (emitted for the K/V DMAs) guarantees residency one tile
// later. r10 taught: bias-via-DMA costs occupancy (58 KB -> 2 blk/CU) and
// doubles barriers -> regression; this gets unsinkability with zero LDS cost.
__global__ __attribute__((amdgpu_flat_work_group_size(512, 512), amdgpu_waves_per_eu(4, 4)))
void attn_kernel(const unsigned short* __restrict__ q,   // [B,NH,S,DK]
                 const unsigned short* __restrict__ k,   // [B,NH,S,DK]
                 const unsigned short* __restrict__ vt,  // [B,NH,DK,S]
                 const float* __restrict__ bias,         // [B,NH,S,S]
                 unsigned short* __restrict__ o)         // [B,S,HID] bf16
{
  __shared__ __align__(16) unsigned short sK[2][64 * 64];  // 2 x 8 KB, swizzled
  __shared__ __align__(16) unsigned short sV[2][64 * 64];  // 2 x 8 KB, swizzled
  __shared__ __align__(16) unsigned int sP[8][16][36];     // 18 KB packed-P (per wave)

  const int p = blockIdx.x;
  const int xcd = p & 7;
  const int g = p >> 3;                   // 0..63
  const int bh = ((g >> 3) << 3) | xcd;   // 8 bh per XCD (bijective)
  const int qblk = g & 7;
  const int tid = threadIdx.x;
  const int wave = tid >> 6, lane = tid & 63;
  const int quad = lane >> 4, l16 = lane & 15;
  const int b = bh >> 4, h = bh & 15;

  const unsigned short* qh = q + (size_t)bh * Sd * DKd;
  const unsigned short* kh = k + (size_t)bh * Sd * DKd;
  const unsigned short* vh = vt + (size_t)bh * DKd * Sd;
  const float* bias_h = bias + (size_t)bh * Sd * Sd;
  const int rq = qblk * 128 + wave * 16;
  unsigned int (*sPw)[36] = sP[wave];

  const int srow = wave * 8 + (lane >> 3);
  const int sslot = (lane & 7) ^ (srow & 7);
  const unsigned short* srcK = kh + (size_t)srow * DKd + sslot * 8;
  const unsigned short* srcV = vh + (size_t)srow * Sd + sslot * 8;
  unsigned short* dK0 = sK[0] + wave * 512;
  unsigned short* dK1 = sK[1] + wave * 512;
  unsigned short* dV0 = sV[0] + wave * 512;
  unsigned short* dV1 = sV[1] + wave * 512;

  const int xs0 = ((0 + quad) ^ (l16 & 7)) * 8;
  const int xs1 = ((4 + quad) ^ (l16 & 7)) * 8;

  bfrag qf[2];
#pragma unroll
  for (int c = 0; c < 2; ++c)
    qf[c] = *(const bfrag*)(qh + (size_t)(rq + l16) * DKd + c * 32 + quad * 8);

  facc oacc[4] = {};
  float lsum = 0.f;
  const float SL2 = SCALEF * L2E;

  const float* bpS = bias_h + (size_t)(rq + l16) * Sd + quad * 4;
  f32x4 br0, br1, br2, br3;
  // prologue: pin-issue bias for tile 0; resident after the first barrier
  bias_load4(br0, bpS + 0);
  bias_load4(br1, bpS + 16);
  bias_load4(br2, bpS + 32);
  bias_load4(br3, bpS + 48);

  gload_lds16(srcK, dK0);
  gload_lds16(srcV, dV0);
  __syncthreads();   // vmcnt(0): K/V tile 0 in LDS, bias tile 0 in VGPRs

  for (int t = 0; t < 16; ++t) {
    const int bb = t & 1;
    if (t < 15) {
      const int kn = (t + 1) * 64;
      gload_lds16(srcK + (size_t)kn * DKd, bb ? dK0 : dK1);
      gload_lds16(srcV + kn, bb ? dV0 : dV1);
    }
    const unsigned short* sKb = sK[bb];
    const unsigned short* sVb = sV[bb];
    facc sacc[4] = {};
#pragma unroll
    for (int j = 0; j < 4; ++j) {
      bfrag kf = *(const bfrag*)(sKb + (j * 16 + l16) * 64 + xs0);
      sacc[j] = __builtin_amdgcn_mfma_f32_16x16x32_bf16(kf, qf[0], sacc[j], 0, 0, 0);
    }
#pragma unroll
    for (int j = 0; j < 4; ++j) {
      bfrag kf = *(const bfrag*)(sKb + (j * 16 + l16) * 64 + xs1);
      sacc[j] = __builtin_amdgcn_mfma_f32_16x16x32_bf16(kf, qf[1], sacc[j], 0, 0, 0);
    }
    // ---- exp/mask on MFMA outputs; bias resident since last barrier ----
    unsigned int pk[4][2];
#pragma unroll
    for (int j = 0; j < 4; ++j) {
      const f32x4 bv = (j == 0) ? br0 : (j == 1) ? br1 : (j == 2) ? br2 : br3;
      float e0 = __builtin_amdgcn_exp2f(fmaf(sacc[j][0], SL2, bv.x * L2E));
      float e1 = __builtin_amdgcn_exp2f(fmaf(sacc[j][1], SL2, bv.y * L2E));
      float e2 = __builtin_amdgcn_exp2f(fmaf(sacc[j][2], SL2, bv.z * L2E));
      float e3 = __builtin_amdgcn_exp2f(fmaf(sacc[j][3], SL2, bv.w * L2E));
      e0 = (sacc[j][0] == 0.f) ? 0.f : e0;
      e1 = (sacc[j][1] == 0.f) ? 0.f : e1;
      e2 = (sacc[j][2] == 0.f) ? 0.f : e2;
      e3 = (sacc[j][3] == 0.f) ? 0.f : e3;
      lsum += (e0 + e1) + (e2 + e3);
      pk[j][0] = (unsigned int)f2bf(e0) | ((unsigned int)f2bf(e1) << 16);
      pk[j][1] = (unsigned int)f2bf(e2) | ((unsigned int)f2bf(e3) << 16);
    }
    // ---- pin-issue bias for t+1 (after last use of br, before the barrier) ----
    if (t < 15) {
      const float* bpn = bpS + (t + 1) * 64;
      bias_load4(br0, bpn + 0);
      bias_load4(br1, bpn + 16);
      bias_load4(br2, bpn + 32);
      bias_load4(br3, bpn + 48);
    }
#pragma unroll
    for (int j = 0; j < 4; ++j) {
      uint2 w; w.x = pk[j][0]; w.y = pk[j][1];
      *(uint2*)&sPw[l16][j * 8 + quad * 2] = w;
    }
#pragma unroll
    for (int c = 0; c < 2; ++c) {
      bfrag pf = *(const bfrag*)&sPw[l16][c * 16 + quad * 4];
      const int xsc = c ? xs1 : xs0;
#pragma unroll
      for (int n = 0; n < 4; ++n) {
        bfrag vf = *(const bfrag*)(sVb + (n * 16 + l16) * 64 + xsc);
        oacc[n] = __builtin_amdgcn_mfma_f32_16x16x32_bf16(vf, pf, oacc[n], 0, 0, 0);
      }
    }
    __syncthreads();   // vmcnt(0) drains K/V DMA + bias loads for t+1
  }

  lsum += __shfl_xor(lsum, 16, 64);
  lsum += __shfl_xor(lsum, 32, 64);
  const float rinv = 1.0f / lsum;

  const size_t rowo = (size_t)(b * Sd + rq + l16) * Hd + h * 64 + quad * 4;
#pragma unroll
  for (int n = 0; n < 4; ++n) {
    ushort4 st;
    st.x = f2bf(oacc[n][0] * rinv);
    st.y = f2bf(oacc[n][1] * rinv);
    st.z = f2bf(oacc[n][2] * rinv);
    st.w = f2bf(oacc[n][3] * rinv);
    *(ushort4*)(o + rowo + n * 16) = st;
  }
}

extern "C" void kernel_launch(void* const* d_in, const int* in_sizes, int n_in,
                              void* d_out, int out_size, void* d_ws, size_t ws_size,
                              hipStream_t stream) {
  const float* batch = (const float*)d_in[0];
  const float* attn_bias = (const float*)d_in[1];
  const float* Wq = (const float*)d_in[2];
  const float* bq = (const float*)d_in[3];
  const float* Wk = (const float*)d_in[4];
  const float* bk = (const float*)d_in[5];
  const float* Wv = (const float*)d_in[6];
  const float* bv = (const float*)d_in[7];
  const float* Wo = (const float*)d_in[8];
  const float* bo = (const float*)d_in[9];
  float* out = (float*)d_out;

  unsigned short* ws = (unsigned short*)d_ws;
  unsigned short* Ab  = ws;                 // 4096x1024
  unsigned short* Wqb = Ab  + 4194304;      // 1024x1024 each
  unsigned short* Wkb = Wqb + 1048576;
  unsigned short* Wvb = Wkb + 1048576;
  unsigned short* Wob = Wvb + 1048576;
  unsigned short* qb  = Wob + 1048576;      // [B,NH,S,DK]
  unsigned short* kb  = qb  + 4194304;
  unsigned short* vtb = kb  + 4194304;      // [B,NH,DK,S]
  unsigned short* ob  = vtb + 4194304;      // [B,S,HID]

  castk_all<<<8192, 256, 0, stream>>>(batch, Wq, Wk, Wv, Wo, Ab, Wqb, Wkb, Wvb, Wob);
  gemm_qkv<<<dim3(32, 8, 3), 256, 0, stream>>>(Ab, Wqb, Wkb, Wvb, bq, bk, bv, qb, kb, vtb);
  attn_kernel<<<dim3(512), 512, 0, stream>>>(qb, kb, vtb, attn_bias, ob);
  gemm_out<<<dim3(64, 8), 256, 0, stream>>>(ob, Wob, bo, out);
}

// Round 12
// 463.155 us; speedup vs baseline: 1.0326x; 1.0125x over previous
//
#include <hip/hip_runtime.h>
#include <hip/hip_bf16.h>
#include <stdint.h>
#include <stddef.h>

#define Bd  4
#define Sd  1024
#define Hd  1024
#define NHd 16
#define DKd 64
#define SCALEF 0.125f
#define NEGV  -9.0e15f
#define L2E   1.4426950408889634f

typedef __attribute__((ext_vector_type(8))) short bfrag;   // 8 bf16 = 4 VGPRs (MFMA A/B)
typedef __attribute__((ext_vector_type(4))) float facc;    // 4 fp32 (MFMA C/D)
typedef __attribute__((ext_vector_type(4))) float f32x4;   // clang-native float4

typedef __attribute__((address_space(1))) const unsigned int ga_u32;
typedef __attribute__((address_space(3))) unsigned int ls_u32;

__device__ __forceinline__ void gload_lds16(const void* g, void* l) {
  // async global->LDS: global addr per-lane, LDS dest = wave-uniform base + lane*16
  __builtin_amdgcn_global_load_lds((ga_u32*)g, (ls_u32*)l, 16, 0, 0);
}

// bias load pinned at issue site; also keeps the VMEM FIFO count exact so the
// hand-counted s_waitcnt vmcnt(N) below is sound (compiler can't reorder
// asm-volatile ops relative to each other).
__device__ __forceinline__ void bias_load4(f32x4& dst, const float* p) {
  asm volatile("global_load_dwordx4 %0, %1, off" : "=v"(dst) : "v"(p));
}

__device__ __forceinline__ unsigned short f2bf(float f) {
  unsigned int u = __float_as_uint(f);
  u += 0x7fffu + ((u >> 16) & 1u);   // RNE
  return (unsigned short)(u >> 16);
}

// ---------------- fused cast fp32 -> bf16, all 5 arrays, one launch ----------------
__global__ void castk_all(const float* __restrict__ s0, const float* __restrict__ s1,
                          const float* __restrict__ s2, const float* __restrict__ s3,
                          const float* __restrict__ s4,
                          unsigned short* __restrict__ d0, unsigned short* __restrict__ d1,
                          unsigned short* __restrict__ d2, unsigned short* __restrict__ d3,
                          unsigned short* __restrict__ d4) {
  const int id = blockIdx.x;
  const float* s; unsigned short* d; int i;
  if (id < 4096) { s = s0; d = d0; i = id * 256 + threadIdx.x; }
  else {
    const int w = (id - 4096) >> 10;
    s = (w == 0) ? s1 : (w == 1) ? s2 : (w == 2) ? s3 : s4;
    d = (w == 0) ? d1 : (w == 1) ? d2 : (w == 2) ? d3 : d4;
    i = ((id - 4096) & 1023) * 256 + threadIdx.x;
  }
  float4 v = ((const float4*)s)[i];
  ushort4 ov;
  ov.x = f2bf(v.x); ov.y = f2bf(v.y); ov.z = f2bf(v.z); ov.w = f2bf(v.w);
  ((ushort4*)d)[i] = ov;
}

// ---------------- fused QKV projection GEMM (2-phase double-buffered staging) ----------------
__global__ __launch_bounds__(256, 3)
void gemm_qkv(const unsigned short* __restrict__ A,
              const unsigned short* __restrict__ W0, const unsigned short* __restrict__ W1,
              const unsigned short* __restrict__ W2,
              const float* __restrict__ b0, const float* __restrict__ b1, const float* __restrict__ b2,
              unsigned short* __restrict__ o0, unsigned short* __restrict__ o1, unsigned short* __restrict__ o2) {
  __shared__ __align__(16) unsigned short smem[128 * 136];
  const int z = blockIdx.z;
  const unsigned short* Bm = (z == 0) ? W0 : (z == 1) ? W1 : W2;
  const float* bias = (z == 0) ? b0 : (z == 1) ? b1 : b2;
  unsigned short* out = (z == 0) ? o0 : (z == 1) ? o1 : o2;

  const int m0 = blockIdx.x * 128, n0 = blockIdx.y * 128;
  const int tid = threadIdx.x;
  const int wave = tid >> 6, lane = tid & 63;
  const int quad = lane >> 4, l16 = lane & 15;
  const int wm = wave >> 1, wn = wave & 1;

  facc acc[4][4] = {};

  const int j0 = wave * 128 + lane;
  const int j1 = j0 + 64;
  const int row0 = j0 >> 2, ko0 = (j0 & 3) << 3;
  const int row1 = j1 >> 2, ko1 = (j1 & 3) << 3;
  const size_t aoff0 = (size_t)(m0 + row0) * 1024 + ko0;
  const size_t aoff1 = (size_t)(m0 + row1) * 1024 + ko1;
  const size_t boff0 = (size_t)(n0 + row0) * 1024 + ko0;
  const size_t boff1 = (size_t)(n0 + row1) * 1024 + ko1;

  const int stA = (wave * 2 + 0) * 512;
  const int stA1i = (wave * 2 + 1) * 512;

  gload_lds16(A + aoff0, smem + stA);
  gload_lds16(A + aoff1, smem + stA1i);
  gload_lds16(Bm + boff0, smem + 8192 + stA);
  gload_lds16(Bm + boff1, smem + 8192 + stA1i);
  __syncthreads();

  for (int k0 = 0; k0 < 1024; k0 += 32) {
    const int cur = (k0 >> 5) & 1;
    const int nxt = cur ^ 1;
    if (k0 < 992) {
      unsigned short* dA = smem + nxt * 4096;
      unsigned short* dB = smem + 8192 + nxt * 4096;
      gload_lds16(A + aoff0 + k0 + 32, dA + stA);
      gload_lds16(A + aoff1 + k0 + 32, dA + stA1i);
      gload_lds16(Bm + boff0 + k0 + 32, dB + stA);
      gload_lds16(Bm + boff1 + k0 + 32, dB + stA1i);
    }
    const unsigned short* sA = smem + cur * 4096;
    const unsigned short* sB = smem + 8192 + cur * 4096;
    bfrag af[4], bf[4];
#pragma unroll
    for (int i = 0; i < 4; ++i) af[i] = *(const bfrag*)(sA + (wm * 64 + i * 16 + l16) * 32 + quad * 8);
#pragma unroll
    for (int j = 0; j < 4; ++j) bf[j] = *(const bfrag*)(sB + (wn * 64 + j * 16 + l16) * 32 + quad * 8);
#pragma unroll
    for (int i = 0; i < 4; ++i)
#pragma unroll
      for (int j = 0; j < 4; ++j)
        acc[i][j] = __builtin_amdgcn_mfma_f32_16x16x32_bf16(af[i], bf[j], acc[i][j], 0, 0, 0);
    __syncthreads();
  }

  if (z < 2) {
#pragma unroll
    for (int i = 0; i < 4; ++i)
#pragma unroll
      for (int j = 0; j < 4; ++j) {
        const int col = n0 + wn * 64 + j * 16 + l16;
        const float bv = bias[col];
        const int h = col >> 6, d = col & 63;
#pragma unroll
        for (int r = 0; r < 4; ++r) {
          const int m = m0 + wm * 64 + i * 16 + quad * 4 + r;
          const int b = m >> 10, s = m & 1023;
          out[(((size_t)(b * NHd + h) * Sd) + s) * DKd + d] = f2bf(acc[i][j][r] + bv);
        }
      }
  } else {
    unsigned short* sT = smem;  // 128 x 136 (padded), reuses dbuf area (post-barrier)
#pragma unroll
    for (int i = 0; i < 4; ++i)
#pragma unroll
      for (int j = 0; j < 4; ++j) {
        const int col = n0 + wn * 64 + j * 16 + l16;
        const float bv = bias[col];
        const int nrow = wn * 64 + j * 16 + l16;
        const int mbase = wm * 64 + i * 16 + quad * 4;
        ushort4 pk;
        pk.x = f2bf(acc[i][j][0] + bv);
        pk.y = f2bf(acc[i][j][1] + bv);
        pk.z = f2bf(acc[i][j][2] + bv);
        pk.w = f2bf(acc[i][j][3] + bv);
        *(ushort4*)(sT + nrow * 136 + mbase) = pk;
      }
    __syncthreads();
    const int bI = m0 >> 10, s0i = m0 & 1023;
#pragma unroll
    for (int it = 0; it < 8; ++it) {
      const int c = tid + it * 256;
      const int row = c >> 4, mc = (c & 15) * 8;
      bfrag vv = *(const bfrag*)(sT + row * 136 + mc);
      const int col = n0 + row, hh = col >> 6, dd = col & 63;
      *(bfrag*)(out + (((size_t)(bI * NHd + hh) * DKd) + dd) * Sd + s0i + mc) = vv;
    }
  }
}

// ---------------- output projection GEMM: 64x128 tile, BK=64, swizzled LDS, 2-phase ----------------
__global__ __launch_bounds__(256, 3)
void gemm_out(const unsigned short* __restrict__ A, const unsigned short* __restrict__ Bm,
              const float* __restrict__ bias, float* __restrict__ out) {
  __shared__ __align__(16) unsigned short smem[24576];
  const int m0 = blockIdx.x * 64, n0 = blockIdx.y * 128;
  const int tid = threadIdx.x;
  const int wave = tid >> 6, lane = tid & 63;
  const int quad = lane >> 4, l16 = lane & 15;

  facc acc[8] = {};

  const int cA0 = (wave * 2 + 0) * 64 + lane;
  const int cA1 = (wave * 2 + 1) * 64 + lane;
  const int rA0 = cA0 >> 3, kA0 = ((cA0 & 7) ^ (rA0 & 7)) * 8;
  const int rA1 = cA1 >> 3, kA1 = ((cA1 & 7) ^ (rA1 & 7)) * 8;
  const size_t aoff0 = (size_t)(m0 + rA0) * 1024 + kA0;
  const size_t aoff1 = (size_t)(m0 + rA1) * 1024 + kA1;
  size_t boff[4];
#pragma unroll
  for (int i = 0; i < 4; ++i) {
    const int c = (wave * 4 + i) * 64 + lane;
    const int r = c >> 3, kk = ((c & 7) ^ (r & 7)) * 8;
    boff[i] = (size_t)(n0 + r) * 1024 + kk;
  }

  const int stA0 = (wave * 2 + 0) * 512;
  const int stA1i = (wave * 2 + 1) * 512;

  gload_lds16(A + aoff0, smem + stA0);
  gload_lds16(A + aoff1, smem + stA1i);
#pragma unroll
  for (int i = 0; i < 4; ++i)
    gload_lds16(Bm + boff[i], smem + 8192 + (wave * 4 + i) * 512);
  __syncthreads();

  for (int k0 = 0; k0 < 1024; k0 += 64) {
    const int cur = (k0 >> 6) & 1;
    const int nxt = cur ^ 1;
    if (k0 < 960) {
      unsigned short* dA = smem + nxt * 4096;
      unsigned short* dB = smem + 8192 + nxt * 8192;
      gload_lds16(A + aoff0 + k0 + 64, dA + stA0);
      gload_lds16(A + aoff1 + k0 + 64, dA + stA1i);
#pragma unroll
      for (int i = 0; i < 4; ++i)
        gload_lds16(Bm + boff[i] + k0 + 64, dB + (wave * 4 + i) * 512);
    }
    const unsigned short* sA = smem + cur * 4096;
    const unsigned short* sB = smem + 8192 + cur * 8192;
#pragma unroll
    for (int c2 = 0; c2 < 2; ++c2) {
      const int ko = ((c2 * 4 + quad) ^ (l16 & 7)) * 8;   // unswizzle
      bfrag af = *(const bfrag*)(sA + (wave * 16 + l16) * 64 + ko);
#pragma unroll
      for (int j = 0; j < 8; ++j) {
        bfrag bf = *(const bfrag*)(sB + (j * 16 + l16) * 64 + ko);
        acc[j] = __builtin_amdgcn_mfma_f32_16x16x32_bf16(af, bf, acc[j], 0, 0, 0);
      }
    }
    __syncthreads();
  }

#pragma unroll
  for (int j = 0; j < 8; ++j) {
    const int col = n0 + j * 16 + l16;
    const float bv = bias[col];
#pragma unroll
    for (int r = 0; r < 4; ++r) {
      const int m = m0 + wave * 16 + quad * 4 + r;
      out[(size_t)m * 1024 + col] = acc[j][r] + bv;
    }
  }
}

// ---------------- fused flash attention: LDS K/V + counted-vmcnt barrier (T4) ----------------
// r9 structure (kv=64, 16 tiles, 50 KB LDS, 3 blocks/CU) with the tile barrier
// changed from __syncthreads (s_waitcnt vmcnt(0): drains the bias loads issued
// ~400cy earlier -> all 8 waves eat the residual HBM latency every tile, the
// r11 regression) to counted vmcnt + raw s_barrier:
//   end of tile:  s_waitcnt vmcnt(4)  -> waits K/V DMAs (oldest 2 in FIFO,
//                 issued a full tile ago), leaves the 4 bias loads IN FLIGHT
//   next tile's exp phase: s_waitcnt vmcnt(2) -> drains bias (K/V DMA for
//                 t+2, issued at top, stays in flight)
// Bias latency coverage grows ~400cy -> ~900+cy. asm-volatile bias loads keep
// the FIFO count exact (compiler can't reorder them). sched_barrier(0) after
// the exp-side wait stops hipcc hoisting br-consumers above it (rule #18).
// Race check: each wave's sK/sV ds_reads are consumed by MFMAs (lgkmcnt-
// forced) before it reaches the barrier; DMA into a buffer is issued only
// after the barrier that ends all reads of it.
__global__ __attribute__((amdgpu_flat_work_group_size(512, 512), amdgpu_waves_per_eu(4, 4)))
void attn_kernel(const unsigned short* __restrict__ q,   // [B,NH,S,DK]
                 const unsigned short* __restrict__ k,   // [B,NH,S,DK]
                 const unsigned short* __restrict__ vt,  // [B,NH,DK,S]
                 const float* __restrict__ bias,         // [B,NH,S,S]
                 unsigned short* __restrict__ o)         // [B,S,HID] bf16
{
  __shared__ __align__(16) unsigned short sK[2][64 * 64];  // 2 x 8 KB, swizzled
  __shared__ __align__(16) unsigned short sV[2][64 * 64];  // 2 x 8 KB, swizzled
  __shared__ __align__(16) unsigned int sP[8][16][36];     // 18 KB packed-P (per wave)

  const int p = blockIdx.x;
  const int xcd = p & 7;
  const int g = p >> 3;                   // 0..63
  const int bh = ((g >> 3) << 3) | xcd;   // 8 bh per XCD (bijective)
  const int qblk = g & 7;
  const int tid = threadIdx.x;
  const int wave = tid >> 6, lane = tid & 63;
  const int quad = lane >> 4, l16 = lane & 15;
  const int b = bh >> 4, h = bh & 15;

  const unsigned short* qh = q + (size_t)bh * Sd * DKd;
  const unsigned short* kh = k + (size_t)bh * Sd * DKd;
  const unsigned short* vh = vt + (size_t)bh * DKd * Sd;
  const float* bias_h = bias + (size_t)bh * Sd * Sd;
  const int rq = qblk * 128 + wave * 16;
  unsigned int (*sPw)[36] = sP[wave];

  const int srow = wave * 8 + (lane >> 3);
  const int sslot = (lane & 7) ^ (srow & 7);
  const unsigned short* srcK = kh + (size_t)srow * DKd + sslot * 8;
  const unsigned short* srcV = vh + (size_t)srow * Sd + sslot * 8;
  unsigned short* dK0 = sK[0] + wave * 512;
  unsigned short* dK1 = sK[1] + wave * 512;
  unsigned short* dV0 = sV[0] + wave * 512;
  unsigned short* dV1 = sV[1] + wave * 512;

  const int xs0 = ((0 + quad) ^ (l16 & 7)) * 8;
  const int xs1 = ((4 + quad) ^ (l16 & 7)) * 8;

  bfrag qf[2];
#pragma unroll
  for (int c = 0; c < 2; ++c)
    qf[c] = *(const bfrag*)(qh + (size_t)(rq + l16) * DKd + c * 32 + quad * 8);

  facc oacc[4] = {};
  float lsum = 0.f;
  const float SL2 = SCALEF * L2E;

  const float* bpS = bias_h + (size_t)(rq + l16) * Sd + quad * 4;
  f32x4 br0, br1, br2, br3;
  // prologue: bias tile 0 + K/V tile 0; __syncthreads drains everything
  bias_load4(br0, bpS + 0);
  bias_load4(br1, bpS + 16);
  bias_load4(br2, bpS + 32);
  bias_load4(br3, bpS + 48);
  gload_lds16(srcK, dK0);
  gload_lds16(srcV, dV0);
  __syncthreads();   // vmcnt(0): K/V tile 0 in LDS, bias tile 0 in VGPRs

  for (int t = 0; t < 16; ++t) {
    const int bb = t & 1;
    // ---- top: issue K/V DMA for t+1 (outstanding: [bias(t) x4?drained] + 2) ----
    if (t < 15) {
      const int kn = (t + 1) * 64;
      gload_lds16(srcK + (size_t)kn * DKd, bb ? dK0 : dK1);
      gload_lds16(srcV + kn, bb ? dV0 : dV1);
    }
    const unsigned short* sKb = sK[bb];
    const unsigned short* sVb = sV[bb];
    facc sacc[4] = {};
#pragma unroll
    for (int j = 0; j < 4; ++j) {
      bfrag kf = *(const bfrag*)(sKb + (j * 16 + l16) * 64 + xs0);
      sacc[j] = __builtin_amdgcn_mfma_f32_16x16x32_bf16(kf, qf[0], sacc[j], 0, 0, 0);
    }
#pragma unroll
    for (int j = 0; j < 4; ++j) {
      bfrag kf = *(const bfrag*)(sKb + (j * 16 + l16) * 64 + xs1);
      sacc[j] = __builtin_amdgcn_mfma_f32_16x16x32_bf16(kf, qf[1], sacc[j], 0, 0, 0);
    }
    // ---- wait for bias(t): leave the K/V DMA for t+1 in flight ----
    if (t < 15) asm volatile("s_waitcnt vmcnt(2)" ::: "memory");
    else        asm volatile("s_waitcnt vmcnt(0)" ::: "memory");
    __builtin_amdgcn_sched_barrier(0);   // rule #18: don't hoist br users above the wait
    // ---- exp/mask on MFMA outputs ----
    unsigned int pk[4][2];
#pragma unroll
    for (int j = 0; j < 4; ++j) {
      const f32x4 bv = (j == 0) ? br0 : (j == 1) ? br1 : (j == 2) ? br2 : br3;
      float e0 = __builtin_amdgcn_exp2f(fmaf(sacc[j][0], SL2, bv.x * L2E));
      float e1 = __builtin_amdgcn_exp2f(fmaf(sacc[j][1], SL2, bv.y * L2E));
      float e2 = __builtin_amdgcn_exp2f(fmaf(sacc[j][2], SL2, bv.z * L2E));
      float e3 = __builtin_amdgcn_exp2f(fmaf(sacc[j][3], SL2, bv.w * L2E));
      e0 = (sacc[j][0] == 0.f) ? 0.f : e0;
      e1 = (sacc[j][1] == 0.f) ? 0.f : e1;
      e2 = (sacc[j][2] == 0.f) ? 0.f : e2;
      e3 = (sacc[j][3] == 0.f) ? 0.f : e3;
      lsum += (e0 + e1) + (e2 + e3);
      pk[j][0] = (unsigned int)f2bf(e0) | ((unsigned int)f2bf(e1) << 16);
      pk[j][1] = (unsigned int)f2bf(e2) | ((unsigned int)f2bf(e3) << 16);
    }
    // ---- issue bias(t+1): stays in flight across the tile barrier ----
    if (t < 15) {
      const float* bpn = bpS + (t + 1) * 64;
      bias_load4(br0, bpn + 0);
      bias_load4(br1, bpn + 16);
      bias_load4(br2, bpn + 32);
      bias_load4(br3, bpn + 48);
    }
#pragma unroll
    for (int j = 0; j < 4; ++j) {
      uint2 w; w.x = pk[j][0]; w.y = pk[j][1];
      *(uint2*)&sPw[l16][j * 8 + quad * 2] = w;
    }
#pragma unroll
    for (int c = 0; c < 2; ++c) {
      bfrag pf = *(const bfrag*)&sPw[l16][c * 16 + quad * 4];
      const int xsc = c ? xs1 : xs0;
#pragma unroll
      for (int n = 0; n < 4; ++n) {
        bfrag vf = *(const bfrag*)(sVb + (n * 16 + l16) * 64 + xsc);
        oacc[n] = __builtin_amdgcn_mfma_f32_16x16x32_bf16(vf, pf, oacc[n], 0, 0, 0);
      }
    }
    // ---- counted-vmcnt barrier: K/V(t+1) drained, bias(t+1) stays in flight ----
    if (t < 15) {
      asm volatile("s_waitcnt vmcnt(4)" ::: "memory");
      __builtin_amdgcn_s_barrier();
    }
  }

  lsum += __shfl_xor(lsum, 16, 64);
  lsum += __shfl_xor(lsum, 32, 64);
  const float rinv = 1.0f / lsum;

  const size_t rowo = (size_t)(b * Sd + rq + l16) * Hd + h * 64 + quad * 4;
#pragma unroll
  for (int n = 0; n < 4; ++n) {
    ushort4 st;
    st.x = f2bf(oacc[n][0] * rinv);
    st.y = f2bf(oacc[n][1] * rinv);
    st.z = f2bf(oacc[n][2] * rinv);
    st.w = f2bf(oacc[n][3] * rinv);
    *(ushort4*)(o + rowo + n * 16) = st;
  }
}

extern "C" void kernel_launch(void* const* d_in, const int* in_sizes, int n_in,
                              void* d_out, int out_size, void* d_ws, size_t ws_size,
                              hipStream_t stream) {
  const float* batch = (const float*)d_in[0];
  const float* attn_bias = (const float*)d_in[1];
  const float* Wq = (const float*)d_in[2];
  const float* bq = (const float*)d_in[3];
  const float* Wk = (const float*)d_in[4];
  const float* bk = (const float*)d_in[5];
  const float* Wv = (const float*)d_in[6];
  const float* bv = (const float*)d_in[7];
  const float* Wo = (const float*)d_in[8];
  const float* bo = (const float*)d_in[9];
  float* out = (float*)d_out;

  unsigned short* ws = (unsigned short*)d_ws;
  unsigned short* Ab  = ws;                 // 4096x1024
  unsigned short* Wqb = Ab  + 4194304;      // 1024x1024 each
  unsigned short* Wkb = Wqb + 1048576;
  unsigned short* Wvb = Wkb + 1048576;
  unsigned short* Wob = Wvb + 1048576;
  unsigned short* qb  = Wob + 1048576;      // [B,NH,S,DK]
  unsigned short* kb  = qb  + 4194304;
  unsigned short* vtb = kb  + 4194304;      // [B,NH,DK,S]
  unsigned short* ob  = vtb + 4194304;      // [B,S,HID]

  castk_all<<<8192, 256, 0, stream>>>(batch, Wq, Wk, Wv, Wo, Ab, Wqb, Wkb, Wvb, Wob);
  gemm_qkv<<<dim3(32, 8, 3), 256, 0, stream>>>(Ab, Wqb, Wkb, Wvb, bq, bk, bv, qb, kb, vtb);
  attn_kernel<<<dim3(512), 512, 0, stream>>>(qb, kb, vtb, attn_bias, ob);
  gemm_out<<<dim3(64, 8), 256, 0, stream>>>(ob, Wob, bo, out);
}

// Round 13
// 450.173 us; speedup vs baseline: 1.0624x; 1.0288x over previous
//
#include <hip/hip_runtime.h>
#include <hip/hip_bf16.h>
#include <stdint.h>
#include <stddef.h>

#define Bd  4
#define Sd  1024
#define Hd  1024
#define NHd 16
#define DKd 64
#define SCALEF 0.125f
#define NEGV  -9.0e15f
#define L2E   1.4426950408889634f

typedef __attribute__((ext_vector_type(8))) short bfrag;   // 8 bf16 = 4 VGPRs (MFMA A/B)
typedef __attribute__((ext_vector_type(4))) float facc;    // 4 fp32 (MFMA C/D)
typedef __attribute__((ext_vector_type(4))) float f32x4;   // clang-native float4 (NT-load OK)

typedef __attribute__((address_space(1))) const unsigned int ga_u32;
typedef __attribute__((address_space(3))) unsigned int ls_u32;

__device__ __forceinline__ void gload_lds16(const void* g, void* l) {
  // async global->LDS: global addr per-lane, LDS dest = wave-uniform base + lane*16
  __builtin_amdgcn_global_load_lds((ga_u32*)g, (ls_u32*)l, 16, 0, 0);
}

__device__ __forceinline__ unsigned short f2bf(float f) {
  unsigned int u = __float_as_uint(f);
  u += 0x7fffu + ((u >> 16) & 1u);   // RNE
  return (unsigned short)(u >> 16);
}

// ---------------- fused cast fp32 -> bf16, all 5 arrays, one launch ----------------
__global__ void castk_all(const float* __restrict__ s0, const float* __restrict__ s1,
                          const float* __restrict__ s2, const float* __restrict__ s3,
                          const float* __restrict__ s4,
                          unsigned short* __restrict__ d0, unsigned short* __restrict__ d1,
                          unsigned short* __restrict__ d2, unsigned short* __restrict__ d3,
                          unsigned short* __restrict__ d4) {
  const int id = blockIdx.x;
  const float* s; unsigned short* d; int i;
  if (id < 4096) { s = s0; d = d0; i = id * 256 + threadIdx.x; }
  else {
    const int w = (id - 4096) >> 10;
    s = (w == 0) ? s1 : (w == 1) ? s2 : (w == 2) ? s3 : s4;
    d = (w == 0) ? d1 : (w == 1) ? d2 : (w == 2) ? d3 : d4;
    i = ((id - 4096) & 1023) * 256 + threadIdx.x;
  }
  float4 v = ((const float4*)s)[i];
  ushort4 ov;
  ov.x = f2bf(v.x); ov.y = f2bf(v.y); ov.z = f2bf(v.z); ov.w = f2bf(v.w);
  ((ushort4*)d)[i] = ov;
}

// ---------------- fused QKV projection GEMM (2-phase double-buffered staging) ----------------
__global__ __launch_bounds__(256, 3)
void gemm_qkv(const unsigned short* __restrict__ A,
              const unsigned short* __restrict__ W0, const unsigned short* __restrict__ W1,
              const unsigned short* __restrict__ W2,
              const float* __restrict__ b0, const float* __restrict__ b1, const float* __restrict__ b2,
              unsigned short* __restrict__ o0, unsigned short* __restrict__ o1, unsigned short* __restrict__ o2) {
  __shared__ __align__(16) unsigned short smem[128 * 136];
  const int z = blockIdx.z;
  const unsigned short* Bm = (z == 0) ? W0 : (z == 1) ? W1 : W2;
  const float* bias = (z == 0) ? b0 : (z == 1) ? b1 : b2;
  unsigned short* out = (z == 0) ? o0 : (z == 1) ? o1 : o2;

  const int m0 = blockIdx.x * 128, n0 = blockIdx.y * 128;
  const int tid = threadIdx.x;
  const int wave = tid >> 6, lane = tid & 63;
  const int quad = lane >> 4, l16 = lane & 15;
  const int wm = wave >> 1, wn = wave & 1;

  facc acc[4][4] = {};

  const int j0 = wave * 128 + lane;
  const int j1 = j0 + 64;
  const int row0 = j0 >> 2, ko0 = (j0 & 3) << 3;
  const int row1 = j1 >> 2, ko1 = (j1 & 3) << 3;
  const size_t aoff0 = (size_t)(m0 + row0) * 1024 + ko0;
  const size_t aoff1 = (size_t)(m0 + row1) * 1024 + ko1;
  const size_t boff0 = (size_t)(n0 + row0) * 1024 + ko0;
  const size_t boff1 = (size_t)(n0 + row1) * 1024 + ko1;

  const int stA = (wave * 2 + 0) * 512;
  const int stA1i = (wave * 2 + 1) * 512;

  gload_lds16(A + aoff0, smem + stA);
  gload_lds16(A + aoff1, smem + stA1i);
  gload_lds16(Bm + boff0, smem + 8192 + stA);
  gload_lds16(Bm + boff1, smem + 8192 + stA1i);
  __syncthreads();

  for (int k0 = 0; k0 < 1024; k0 += 32) {
    const int cur = (k0 >> 5) & 1;
    const int nxt = cur ^ 1;
    if (k0 < 992) {
      unsigned short* dA = smem + nxt * 4096;
      unsigned short* dB = smem + 8192 + nxt * 4096;
      gload_lds16(A + aoff0 + k0 + 32, dA + stA);
      gload_lds16(A + aoff1 + k0 + 32, dA + stA1i);
      gload_lds16(Bm + boff0 + k0 + 32, dB + stA);
      gload_lds16(Bm + boff1 + k0 + 32, dB + stA1i);
    }
    const unsigned short* sA = smem + cur * 4096;
    const unsigned short* sB = smem + 8192 + cur * 4096;
    bfrag af[4], bf[4];
#pragma unroll
    for (int i = 0; i < 4; ++i) af[i] = *(const bfrag*)(sA + (wm * 64 + i * 16 + l16) * 32 + quad * 8);
#pragma unroll
    for (int j = 0; j < 4; ++j) bf[j] = *(const bfrag*)(sB + (wn * 64 + j * 16 + l16) * 32 + quad * 8);
#pragma unroll
    for (int i = 0; i < 4; ++i)
#pragma unroll
      for (int j = 0; j < 4; ++j)
        acc[i][j] = __builtin_amdgcn_mfma_f32_16x16x32_bf16(af[i], bf[j], acc[i][j], 0, 0, 0);
    __syncthreads();
  }

  if (z < 2) {
#pragma unroll
    for (int i = 0; i < 4; ++i)
#pragma unroll
      for (int j = 0; j < 4; ++j) {
        const int col = n0 + wn * 64 + j * 16 + l16;
        const float bv = bias[col];
        const int h = col >> 6, d = col & 63;
#pragma unroll
        for (int r = 0; r < 4; ++r) {
          const int m = m0 + wm * 64 + i * 16 + quad * 4 + r;
          const int b = m >> 10, s = m & 1023;
          out[(((size_t)(b * NHd + h) * Sd) + s) * DKd + d] = f2bf(acc[i][j][r] + bv);
        }
      }
  } else {
    unsigned short* sT = smem;  // 128 x 136 (padded), reuses dbuf area (post-barrier)
#pragma unroll
    for (int i = 0; i < 4; ++i)
#pragma unroll
      for (int j = 0; j < 4; ++j) {
        const int col = n0 + wn * 64 + j * 16 + l16;
        const float bv = bias[col];
        const int nrow = wn * 64 + j * 16 + l16;
        const int mbase = wm * 64 + i * 16 + quad * 4;
        ushort4 pk;
        pk.x = f2bf(acc[i][j][0] + bv);
        pk.y = f2bf(acc[i][j][1] + bv);
        pk.z = f2bf(acc[i][j][2] + bv);
        pk.w = f2bf(acc[i][j][3] + bv);
        *(ushort4*)(sT + nrow * 136 + mbase) = pk;
      }
    __syncthreads();
    const int bI = m0 >> 10, s0i = m0 & 1023;
#pragma unroll
    for (int it = 0; it < 8; ++it) {
      const int c = tid + it * 256;
      const int row = c >> 4, mc = (c & 15) * 8;
      bfrag vv = *(const bfrag*)(sT + row * 136 + mc);
      const int col = n0 + row, hh = col >> 6, dd = col & 63;
      *(bfrag*)(out + (((size_t)(bI * NHd + hh) * DKd) + dd) * Sd + s0i + mc) = vv;
    }
  }
}

// ---------------- output projection GEMM: 64x128 tile, BK=64, swizzled LDS, 2-phase ----------------
__global__ __launch_bounds__(256, 3)
void gemm_out(const unsigned short* __restrict__ A, const unsigned short* __restrict__ Bm,
              const float* __restrict__ bias, float* __restrict__ out) {
  __shared__ __align__(16) unsigned short smem[24576];
  const int m0 = blockIdx.x * 64, n0 = blockIdx.y * 128;
  const int tid = threadIdx.x;
  const int wave = tid >> 6, lane = tid & 63;
  const int quad = lane >> 4, l16 = lane & 15;

  facc acc[8] = {};

  const int cA0 = (wave * 2 + 0) * 64 + lane;
  const int cA1 = (wave * 2 + 1) * 64 + lane;
  const int rA0 = cA0 >> 3, kA0 = ((cA0 & 7) ^ (rA0 & 7)) * 8;
  const int rA1 = cA1 >> 3, kA1 = ((cA1 & 7) ^ (rA1 & 7)) * 8;
  const size_t aoff0 = (size_t)(m0 + rA0) * 1024 + kA0;
  const size_t aoff1 = (size_t)(m0 + rA1) * 1024 + kA1;
  size_t boff[4];
#pragma unroll
  for (int i = 0; i < 4; ++i) {
    const int c = (wave * 4 + i) * 64 + lane;
    const int r = c >> 3, kk = ((c & 7) ^ (r & 7)) * 8;
    boff[i] = (size_t)(n0 + r) * 1024 + kk;
  }

  const int stA0 = (wave * 2 + 0) * 512;
  const int stA1i = (wave * 2 + 1) * 512;

  gload_lds16(A + aoff0, smem + stA0);
  gload_lds16(A + aoff1, smem + stA1i);
#pragma unroll
  for (int i = 0; i < 4; ++i)
    gload_lds16(Bm + boff[i], smem + 8192 + (wave * 4 + i) * 512);
  __syncthreads();

  for (int k0 = 0; k0 < 1024; k0 += 64) {
    const int cur = (k0 >> 6) & 1;
    const int nxt = cur ^ 1;
    if (k0 < 960) {
      unsigned short* dA = smem + nxt * 4096;
      unsigned short* dB = smem + 8192 + nxt * 8192;
      gload_lds16(A + aoff0 + k0 + 64, dA + stA0);
      gload_lds16(A + aoff1 + k0 + 64, dA + stA1i);
#pragma unroll
      for (int i = 0; i < 4; ++i)
        gload_lds16(Bm + boff[i] + k0 + 64, dB + (wave * 4 + i) * 512);
    }
    const unsigned short* sA = smem + cur * 4096;
    const unsigned short* sB = smem + 8192 + cur * 8192;
#pragma unroll
    for (int c2 = 0; c2 < 2; ++c2) {
      const int ko = ((c2 * 4 + quad) ^ (l16 & 7)) * 8;   // unswizzle
      bfrag af = *(const bfrag*)(sA + (wave * 16 + l16) * 64 + ko);
#pragma unroll
      for (int j = 0; j < 8; ++j) {
        bfrag bf = *(const bfrag*)(sB + (j * 16 + l16) * 64 + ko);
        acc[j] = __builtin_amdgcn_mfma_f32_16x16x32_bf16(af, bf, acc[j], 0, 0, 0);
      }
    }
    __syncthreads();
  }

#pragma unroll
  for (int j = 0; j < 8; ++j) {
    const int col = n0 + j * 16 + l16;
    const float bv = bias[col];
#pragma unroll
    for (int r = 0; r < 4; ++r) {
      const int m = m0 + wave * 16 + quad * 4 + r;
      out[(size_t)m * 1024 + col] = acc[j][r] + bv;
    }
  }
}

// ---------------- fused flash attention: LDS-staged K/V shared by 8 waves ----------------
// Best-measured configuration (r9, 450.25us total): kv=64, 16 tiles, 50 KB
// LDS -> 3 blocks/CU; NT f32x4 bias loads prefetched one tile ahead with an
// asm residency pin, compiler free to hoist the load issue early (r11/r12
// proved manual issue-pinning only regresses: the compiler already schedules
// the bias loads ahead of QK^T, giving full-tile latency coverage).
__global__ __attribute__((amdgpu_flat_work_group_size(512, 512), amdgpu_waves_per_eu(4, 4)))
void attn_kernel(const unsigned short* __restrict__ q,   // [B,NH,S,DK]
                 const unsigned short* __restrict__ k,   // [B,NH,S,DK]
                 const unsigned short* __restrict__ vt,  // [B,NH,DK,S]
                 const float* __restrict__ bias,         // [B,NH,S,S]
                 unsigned short* __restrict__ o)         // [B,S,HID] bf16
{
  __shared__ __align__(16) unsigned short sK[2][64 * 64];  // 2 x 8 KB, swizzled
  __shared__ __align__(16) unsigned short sV[2][64 * 64];  // 2 x 8 KB, swizzled
  __shared__ __align__(16) unsigned int sP[8][16][36];     // 18 KB packed-P (per wave)

  const int p = blockIdx.x;
  const int xcd = p & 7;
  const int g = p >> 3;                   // 0..63
  const int bh = ((g >> 3) << 3) | xcd;   // 8 bh per XCD (bijective)
  const int qblk = g & 7;
  const int tid = threadIdx.x;
  const int wave = tid >> 6, lane = tid & 63;
  const int quad = lane >> 4, l16 = lane & 15;
  const int b = bh >> 4, h = bh & 15;

  const unsigned short* qh = q + (size_t)bh * Sd * DKd;
  const unsigned short* kh = k + (size_t)bh * Sd * DKd;
  const unsigned short* vh = vt + (size_t)bh * DKd * Sd;
  const float* bias_h = bias + (size_t)bh * Sd * Sd;
  const int rq = qblk * 128 + wave * 16;
  unsigned int (*sPw)[36] = sP[wave];

  const int srow = wave * 8 + (lane >> 3);
  const int sslot = (lane & 7) ^ (srow & 7);
  const unsigned short* srcK = kh + (size_t)srow * DKd + sslot * 8;
  const unsigned short* srcV = vh + (size_t)srow * Sd + sslot * 8;
  unsigned short* dK0 = sK[0] + wave * 512;
  unsigned short* dK1 = sK[1] + wave * 512;
  unsigned short* dV0 = sV[0] + wave * 512;
  unsigned short* dV1 = sV[1] + wave * 512;

  const int xs0 = ((0 + quad) ^ (l16 & 7)) * 8;
  const int xs1 = ((4 + quad) ^ (l16 & 7)) * 8;

  bfrag qf[2];
#pragma unroll
  for (int c = 0; c < 2; ++c)
    qf[c] = *(const bfrag*)(qh + (size_t)(rq + l16) * DKd + c * 32 + quad * 8);

  facc oacc[4] = {};
  float lsum = 0.f;
  const float SL2 = SCALEF * L2E;

  const float* bpS = bias_h + (size_t)(rq + l16) * Sd + quad * 4;
  f32x4 br0 = __builtin_nontemporal_load((const f32x4*)(bpS + 0));
  f32x4 br1 = __builtin_nontemporal_load((const f32x4*)(bpS + 16));
  f32x4 br2 = __builtin_nontemporal_load((const f32x4*)(bpS + 32));
  f32x4 br3 = __builtin_nontemporal_load((const f32x4*)(bpS + 48));

  gload_lds16(srcK, dK0);
  gload_lds16(srcV, dV0);
  __syncthreads();

  for (int t = 0; t < 16; ++t) {
    const int bb = t & 1;
    if (t < 15) {
      const int kn = (t + 1) * 64;
      gload_lds16(srcK + (size_t)kn * DKd, bb ? dK0 : dK1);
      gload_lds16(srcV + kn, bb ? dV0 : dV1);
    }
    const unsigned short* sKb = sK[bb];
    const unsigned short* sVb = sV[bb];
    facc sacc[4] = {};
#pragma unroll
    for (int j = 0; j < 4; ++j) {
      bfrag kf = *(const bfrag*)(sKb + (j * 16 + l16) * 64 + xs0);
      sacc[j] = __builtin_amdgcn_mfma_f32_16x16x32_bf16(kf, qf[0], sacc[j], 0, 0, 0);
    }
#pragma unroll
    for (int j = 0; j < 4; ++j) {
      bfrag kf = *(const bfrag*)(sKb + (j * 16 + l16) * 64 + xs1);
      sacc[j] = __builtin_amdgcn_mfma_f32_16x16x32_bf16(kf, qf[1], sacc[j], 0, 0, 0);
    }
    asm volatile("" : "+v"(br0), "+v"(br1), "+v"(br2), "+v"(br3));
    unsigned int pk[4][2];
#pragma unroll
    for (int j = 0; j < 4; ++j) {
      const f32x4 bv = (j == 0) ? br0 : (j == 1) ? br1 : (j == 2) ? br2 : br3;
      float e0 = __builtin_amdgcn_exp2f(fmaf(sacc[j][0], SL2, bv.x * L2E));
      float e1 = __builtin_amdgcn_exp2f(fmaf(sacc[j][1], SL2, bv.y * L2E));
      float e2 = __builtin_amdgcn_exp2f(fmaf(sacc[j][2], SL2, bv.z * L2E));
      float e3 = __builtin_amdgcn_exp2f(fmaf(sacc[j][3], SL2, bv.w * L2E));
      e0 = (sacc[j][0] == 0.f) ? 0.f : e0;
      e1 = (sacc[j][1] == 0.f) ? 0.f : e1;
      e2 = (sacc[j][2] == 0.f) ? 0.f : e2;
      e3 = (sacc[j][3] == 0.f) ? 0.f : e3;
      lsum += (e0 + e1) + (e2 + e3);
      pk[j][0] = (unsigned int)f2bf(e0) | ((unsigned int)f2bf(e1) << 16);
      pk[j][1] = (unsigned int)f2bf(e2) | ((unsigned int)f2bf(e3) << 16);
    }
    if (t < 15) {
      const float* bpn = bpS + (t + 1) * 64;
      br0 = __builtin_nontemporal_load((const f32x4*)(bpn + 0));
      br1 = __builtin_nontemporal_load((const f32x4*)(bpn + 16));
      br2 = __builtin_nontemporal_load((const f32x4*)(bpn + 32));
      br3 = __builtin_nontemporal_load((const f32x4*)(bpn + 48));
    }
#pragma unroll
    for (int j = 0; j < 4; ++j) {
      uint2 w; w.x = pk[j][0]; w.y = pk[j][1];
      *(uint2*)&sPw[l16][j * 8 + quad * 2] = w;
    }
#pragma unroll
    for (int c = 0; c < 2; ++c) {
      bfrag pf = *(const bfrag*)&sPw[l16][c * 16 + quad * 4];
      const int xsc = c ? xs1 : xs0;
#pragma unroll
      for (int n = 0; n < 4; ++n) {
        bfrag vf = *(const bfrag*)(sVb + (n * 16 + l16) * 64 + xsc);
        oacc[n] = __builtin_amdgcn_mfma_f32_16x16x32_bf16(vf, pf, oacc[n], 0, 0, 0);
      }
    }
    __syncthreads();
  }

  lsum += __shfl_xor(lsum, 16, 64);
  lsum += __shfl_xor(lsum, 32, 64);
  const float rinv = 1.0f / lsum;

  const size_t rowo = (size_t)(b * Sd + rq + l16) * Hd + h * 64 + quad * 4;
#pragma unroll
  for (int n = 0; n < 4; ++n) {
    ushort4 st;
    st.x = f2bf(oacc[n][0] * rinv);
    st.y = f2bf(oacc[n][1] * rinv);
    st.z = f2bf(oacc[n][2] * rinv);
    st.w = f2bf(oacc[n][3] * rinv);
    *(ushort4*)(o + rowo + n * 16) = st;
  }
}

extern "C" void kernel_launch(void* const* d_in, const int* in_sizes, int n_in,
                              void* d_out, int out_size, void* d_ws, size_t ws_size,
                              hipStream_t stream) {
  const float* batch = (const float*)d_in[0];
  const float* attn_bias = (const float*)d_in[1];
  const float* Wq = (const float*)d_in[2];
  const float* bq = (const float*)d_in[3];
  const float* Wk = (const float*)d_in[4];
  const float* bk = (const float*)d_in[5];
  const float* Wv = (const float*)d_in[6];
  const float* bv = (const float*)d_in[7];
  const float* Wo = (const float*)d_in[8];
  const float* bo = (const float*)d_in[9];
  float* out = (float*)d_out;

  unsigned short* ws = (unsigned short*)d_ws;
  unsigned short* Ab  = ws;                 // 4096x1024
  unsigned short* Wqb = Ab  + 4194304;      // 1024x1024 each
  unsigned short* Wkb = Wqb + 1048576;
  unsigned short* Wvb = Wkb + 1048576;
  unsigned short* Wob = Wvb + 1048576;
  unsigned short* qb  = Wob + 1048576;      // [B,NH,S,DK]
  unsigned short* kb  = qb  + 4194304;
  unsigned short* vtb = kb  + 4194304;      // [B,NH,DK,S]
  unsigned short* ob  = vtb + 4194304;      // [B,S,HID]

  castk_all<<<8192, 256, 0, stream>>>(batch, Wq, Wk, Wv, Wo, Ab, Wqb, Wkb, Wvb, Wob);
  gemm_qkv<<<dim3(32, 8, 3), 256, 0, stream>>>(Ab, Wqb, Wkb, Wvb, bq, bk, bv, qb, kb, vtb);
  attn_kernel<<<dim3(512), 512, 0, stream>>>(qb, kb, vtb, attn_bias, ob);
  gemm_out<<<dim3(64, 8), 256, 0, stream>>>(ob, Wob, bo, out);
}